// Round 4
// baseline (1429.288 us; speedup 1.0000x reference)
//
#include <hip/hip_runtime.h>

#define N_OBJ  20000
#define N_ROOM 500
#define N_ATTR 2000
#define IN_F   300
#define HDIM   512
#define E_OO   640000
#define E_RO   50000
#define E_AO   100000
#define BATCH  8

typedef __attribute__((ext_vector_type(8))) __bf16 bf16x8;
typedef __attribute__((ext_vector_type(4))) float  f32x4;

__device__ inline unsigned short f2bf_rn(float x)
{
    unsigned u = __float_as_uint(x);
    unsigned r = (u + 0x7fffu + ((u >> 16) & 1u)) >> 16;
    return (unsigned short)r;
}
__device__ inline float bf2f(unsigned short h)
{
    return __uint_as_float(((unsigned)h) << 16);
}

// ---------------------------------------------------------------------------
// Degree counting (all 3 relations in one grid)
// ---------------------------------------------------------------------------
__global__ void count_edges(const int* __restrict__ src_oo, const int* __restrict__ dst_oo,
                            const int* __restrict__ src_ro, const int* __restrict__ dst_ro,
                            const int* __restrict__ src_ao, const int* __restrict__ dst_ao,
                            int* cnt_src_oo, int* cnt_src_ro, int* cnt_src_ao,
                            int* cnt_dst_oo, int* cnt_dst_ro, int* cnt_dst_ao)
{
    int e = blockIdx.x * blockDim.x + threadIdx.x;
    const int total = E_OO + E_RO + E_AO;
    if (e >= total) return;
    if (e < E_OO) {
        atomicAdd(&cnt_src_oo[src_oo[e]], 1);
        atomicAdd(&cnt_dst_oo[dst_oo[e]], 1);
    } else if (e < E_OO + E_RO) {
        int i = e - E_OO;
        atomicAdd(&cnt_src_ro[src_ro[i]], 1);
        atomicAdd(&cnt_dst_ro[dst_ro[i]], 1);
    } else {
        int i = e - E_OO - E_RO;
        atomicAdd(&cnt_src_ao[src_ao[i]], 1);
        atomicAdd(&cnt_dst_ao[dst_ao[i]], 1);
    }
}

// ---------------------------------------------------------------------------
// Exclusive prefix-sum of the 3 dst-degree arrays
// ---------------------------------------------------------------------------
__global__ __launch_bounds__(1024)
void scan3(const int* c0, const int* c1, const int* c2,
           int* r0, int* r1, int* r2,
           int* u0, int* u1, int* u2)
{
    const int n = N_OBJ;
    const int* cnt = (blockIdx.x == 0) ? c0 : (blockIdx.x == 1 ? c1 : c2);
    int* rp  = (blockIdx.x == 0) ? r0 : (blockIdx.x == 1 ? r1 : r2);
    int* cur = (blockIdx.x == 0) ? u0 : (blockIdx.x == 1 ? u1 : u2);

    __shared__ int part[1024];
    int t  = threadIdx.x;
    int lo = t * 20;
    int hi = lo + 20 < n ? lo + 20 : n;

    int local = 0;
    for (int i = lo; i < hi; ++i) local += cnt[i];
    part[t] = local;
    __syncthreads();
    for (int off = 1; off < 1024; off <<= 1) {
        int v = (t >= off) ? part[t - off] : 0;
        __syncthreads();
        part[t] += v;
        __syncthreads();
    }
    int run = part[t] - local;
    for (int i = lo; i < hi; ++i) {
        rp[i]  = run;
        cur[i] = run;
        run += cnt[i];
    }
    if (t == 1023) rp[n] = part[1023];
}

// ---------------------------------------------------------------------------
// norm = 1/sqrt(max(deg,1)) for the 6 degree arrays
// ---------------------------------------------------------------------------
__global__ void norms6(const int* c0, const int* c1, const int* c2,
                       const int* c3, const int* c4, const int* c5,
                       float* n0, float* n1, float* n2,
                       float* n3, float* n4, float* n5,
                       int s0, int s1, int s2, int s3, int s4, int s5)
{
    const int* c; float* o; int n;
    switch (blockIdx.y) {
        case 0:  c = c0; o = n0; n = s0; break;
        case 1:  c = c1; o = n1; n = s1; break;
        case 2:  c = c2; o = n2; n = s2; break;
        case 3:  c = c3; o = n3; n = s3; break;
        case 4:  c = c4; o = n4; n = s4; break;
        default: c = c5; o = n5; n = s5; break;
    }
    int i = blockIdx.x * blockDim.x + threadIdx.x;
    if (i < n) {
        int d = c[i];
        if (d < 1) d = 1;
        o[i] = 1.0f / sqrtf((float)d);
    }
}

// ---------------------------------------------------------------------------
// Fill CSR column arrays using atomic cursors
// ---------------------------------------------------------------------------
__global__ void fill_edges(const int* __restrict__ src_oo, const int* __restrict__ dst_oo,
                           const int* __restrict__ src_ro, const int* __restrict__ dst_ro,
                           const int* __restrict__ src_ao, const int* __restrict__ dst_ao,
                           int* cur_oo, int* cur_ro, int* cur_ao,
                           int* col_oo, int* col_ro, int* col_ao)
{
    int e = blockIdx.x * blockDim.x + threadIdx.x;
    const int total = E_OO + E_RO + E_AO;
    if (e >= total) return;
    if (e < E_OO) {
        int pos = atomicAdd(&cur_oo[dst_oo[e]], 1);
        col_oo[pos] = src_oo[e];
    } else if (e < E_OO + E_RO) {
        int i = e - E_OO;
        int pos = atomicAdd(&cur_ro[dst_ro[i]], 1);
        col_ro[pos] = src_ro[i];
    } else {
        int i = e - E_OO - E_RO;
        int pos = atomicAdd(&cur_ao[dst_ao[i]], 1);
        col_ao[pos] = src_ao[i];
    }
}

// ---------------------------------------------------------------------------
// Pack weight: Wp is n-major [HDIM][3*Kp] bf16 bits, rows: [Wh | Wl | Wh]
// ---------------------------------------------------------------------------
__global__ void pack_w(const float* __restrict__ W, int K, int Kp,
                       unsigned short* __restrict__ Wp)
{
    int Keff = 3 * Kp;
    int idx = blockIdx.x * 256 + threadIdx.x;
    if (idx >= HDIM * Keff) return;
    int n  = idx / Keff;
    int kp = idx - n * Keff;
    int term = (kp >= 2 * Kp) ? 2 : (kp >= Kp ? 1 : 0);
    int ks = kp - term * Kp;
    float v = (ks < K) ? W[(size_t)ks * HDIM + n] : 0.0f;
    unsigned short h = f2bf_rn(v);
    unsigned short out = (term == 1) ? f2bf_rn(v - bf2f(h)) : h;
    Wp[idx] = out;
}

// ---------------------------------------------------------------------------
// Wave-per-row CSR aggregation, float4 gathers, hi/lo bf16 split output.
// F real width, FP padded (multiple of 4); 4 rows per 256-thread block.
// col[j]/nsrc[s] indices are wave-uniform -> scalar loads.
// ---------------------------------------------------------------------------
template<int F, int FP>
__global__ __launch_bounds__(256)
void agg_split_v4(const float* __restrict__ feat,
                  const int* __restrict__ rp, const int* __restrict__ col,
                  const float* __restrict__ nsrc, const float* __restrict__ ndst,
                  float scale,
                  unsigned short* __restrict__ hi, unsigned short* __restrict__ lo)
{
    constexpr int S  = F / 4;    // real float4 slots
    constexpr int SP = FP / 4;   // padded slots
    int wave = threadIdx.x >> 6, lane = threadIdx.x & 63;
    int d = blockIdx.x * 4 + wave;
    if (d >= N_OBJ) return;
    int a = rp[d], b = rp[d + 1];
    bool has0 = (lane < S);
    bool has1 = (lane + 64 < S);
    f32x4 acc0 = (f32x4)0.0f, acc1 = (f32x4)0.0f;
    for (int j = a; j < b; ++j) {
        int s = col[j];
        float ns = nsrc[s] * scale;
        const float* row = feat + (size_t)s * F;
        if (has0) acc0 += (*(const f32x4*)(row + lane * 4)) * ns;
        if (has1) acc1 += (*(const f32x4*)(row + (lane + 64) * 4)) * ns;
    }
    float nd = ndst[d];
    acc0 *= nd; acc1 *= nd;

    size_t rb = (size_t)d * FP;
    if (lane < SP) {
        f32x4 v = has0 ? acc0 : (f32x4)0.0f;
        ushort4 h, l;
        h.x = f2bf_rn(v.x); l.x = f2bf_rn(v.x - bf2f(h.x));
        h.y = f2bf_rn(v.y); l.y = f2bf_rn(v.y - bf2f(h.y));
        h.z = f2bf_rn(v.z); l.z = f2bf_rn(v.z - bf2f(h.z));
        h.w = f2bf_rn(v.w); l.w = f2bf_rn(v.w - bf2f(h.w));
        *(ushort4*)(hi + rb + lane * 4) = h;
        *(ushort4*)(lo + rb + lane * 4) = l;
    }
    if (lane + 64 < SP) {
        f32x4 v = has1 ? acc1 : (f32x4)0.0f;
        ushort4 h, l;
        h.x = f2bf_rn(v.x); l.x = f2bf_rn(v.x - bf2f(h.x));
        h.y = f2bf_rn(v.y); l.y = f2bf_rn(v.y - bf2f(h.y));
        h.z = f2bf_rn(v.z); l.z = f2bf_rn(v.z - bf2f(h.z));
        h.w = f2bf_rn(v.w); l.w = f2bf_rn(v.w - bf2f(h.w));
        *(ushort4*)(hi + rb + (lane + 64) * 4) = h;
        *(ushort4*)(lo + rb + (lane + 64) * 4) = l;
    }
}

// ---------------------------------------------------------------------------
// Pipelined bf16-split MFMA GEMM, optionally fusing NREL relations with
// per-relation relu + register-space sum (conv1), or broadcasting the result
// into all 8 batch slices (conv2).
//   K_eff per relation = 3*KP: [0,KP)=Ah@Wh, [KP,2KP)=Ah@Wl, [2KP,3KP)=Al@Wh
//   EPI: 0 = C=v (v already relu-summed, NREL==3)
//        2 = C[slice 0..7]=v+bias (NREL==1)
//        3 = C=v+bias (NREL==1, no broadcast)
// Tile 128x128, 4 waves, 4x4 frags of v_mfma_f32_16x16x32_bf16, BK=32.
// ---------------------------------------------------------------------------
template<int KP, int NREL, int EPI>
__global__ __launch_bounds__(256)
void gemm_pipe(const unsigned short* __restrict__ AhA,
               const unsigned short* __restrict__ AlA,
               const unsigned short* __restrict__ AhB,
               const unsigned short* __restrict__ AlB,
               const unsigned short* __restrict__ AhC,
               const unsigned short* __restrict__ AlC,
               const unsigned short* __restrict__ WpA,   // relations 0,1
               const unsigned short* __restrict__ WpB,   // relation 2
               const float* __restrict__ biasA,
               const float* __restrict__ biasB,
               float* __restrict__ C, int M)
{
    constexpr int KEFF = 3 * KP;
    constexpr int NIT  = KEFF / 32;
    constexpr int TOT  = NREL * NIT;
    const int LDT = 40;                      // u16 stride, 80 B rows (2-way banks max)
    __shared__ unsigned short As[128 * LDT];
    __shared__ unsigned short Bs[128 * LDT];

    int tid  = threadIdx.x;
    int lane = tid & 63;
    int wave = tid >> 6;
    int wm = (wave & 1) * 64;
    int wn = (wave >> 1) * 64;
    int m0 = blockIdx.x * 128;
    int n0 = blockIdx.y * 128;
    int rw = lane & 15;
    int q  = lane >> 4;

    int sm = tid >> 2;            // staging row 0..63
    int sk = (tid & 3) * 8;       // staging k-chunk (u16)

    // clamped global rows (garbage rows masked at store)
    int gm0 = m0 + sm;      if (gm0 >= M) gm0 = M - 1;
    int gm1 = m0 + 64 + sm; if (gm1 >= M) gm1 = M - 1;

    f32x4 acc[4][4], sum[4][4];
#pragma unroll
    for (int i = 0; i < 4; ++i)
#pragma unroll
        for (int j = 0; j < 4; ++j) { acc[i][j] = (f32x4)0.0f; sum[i][j] = (f32x4)0.0f; }

    uint4 ra0, ra1, rb0, rb1;
    auto load_tile = [&](int g) {
        int r  = g / NIT;
        int kk = (g - r * NIT) * 32;         // local k within relation
        const unsigned short* Ah = (NREL == 1 || r == 0) ? AhA : (r == 1 ? AhB : AhC);
        const unsigned short* Al = (NREL == 1 || r == 0) ? AlA : (r == 1 ? AlB : AlC);
        const unsigned short* Wp = (NREL == 3 && r == 2) ? WpB : WpA;
        const unsigned short* Asrc = (kk >= 2 * KP) ? Al : Ah;
        int kb = kk - ((kk >= 2 * KP) ? 2 * KP : (kk >= KP ? KP : 0));
        ra0 = *(const uint4*)(Asrc + (size_t)gm0 * KP + kb + sk);
        ra1 = *(const uint4*)(Asrc + (size_t)gm1 * KP + kb + sk);
        rb0 = *(const uint4*)(Wp + (size_t)(n0 + sm) * KEFF + kk + sk);
        rb1 = *(const uint4*)(Wp + (size_t)(n0 + 64 + sm) * KEFF + kk + sk);
    };

    load_tile(0);
    for (int g = 0; g < TOT; ++g) {
        *(uint4*)&As[sm * LDT + sk]        = ra0;
        *(uint4*)&As[(64 + sm) * LDT + sk] = ra1;
        *(uint4*)&Bs[sm * LDT + sk]        = rb0;
        *(uint4*)&Bs[(64 + sm) * LDT + sk] = rb1;
        __syncthreads();
        if (g + 1 < TOT) load_tile(g + 1);   // overlap with MFMAs below

        bf16x8 af[4], bfr[4];
#pragma unroll
        for (int i = 0; i < 4; ++i) {
            af[i]  = __builtin_bit_cast(bf16x8, *(const uint4*)&As[(wm + i * 16 + rw) * LDT + q * 8]);
            bfr[i] = __builtin_bit_cast(bf16x8, *(const uint4*)&Bs[(wn + i * 16 + rw) * LDT + q * 8]);
        }
#pragma unroll
        for (int i = 0; i < 4; ++i)
#pragma unroll
            for (int j = 0; j < 4; ++j)
                acc[i][j] = __builtin_amdgcn_mfma_f32_16x16x32_bf16(af[i], bfr[j], acc[i][j], 0, 0, 0);

        if (NREL == 3 && ((g + 1) % NIT == 0)) {
            // relation r finished: sum += relu(acc + bias_r); acc = 0
            int r = g / NIT;
            const float* bias = (r == 2) ? biasB : biasA;
#pragma unroll
            for (int j = 0; j < 4; ++j) {
                float bv = bias[n0 + wn + j * 16 + rw];
#pragma unroll
                for (int i = 0; i < 4; ++i) {
#pragma unroll
                    for (int t = 0; t < 4; ++t) {
                        sum[i][j][t] += fmaxf(acc[i][j][t] + bv, 0.0f);
                        acc[i][j][t] = 0.0f;
                    }
                }
            }
        }
        __syncthreads();
    }

    const size_t slice = (size_t)N_OBJ * HDIM;
#pragma unroll
    for (int j = 0; j < 4; ++j) {
        int n = n0 + wn + j * 16 + rw;
        float bv = (NREL == 1) ? biasA[n] : 0.0f;
#pragma unroll
        for (int i = 0; i < 4; ++i) {
#pragma unroll
            for (int t = 0; t < 4; ++t) {
                int m = m0 + wm + i * 16 + q * 4 + t;
                if (m < M) {
                    float v = (NREL == 3) ? sum[i][j][t] : acc[i][j][t] + bv;
                    size_t o = (size_t)m * HDIM + n;
                    if (EPI == 2) {
#pragma unroll
                        for (int c = 0; c < BATCH; ++c) C[c * slice + o] = v;
                    } else {
                        C[o] = v;
                    }
                }
            }
        }
    }
}

// ---------------------------------------------------------------------------
// Broadcast slice 0 of d_out into slices 1..7 (fallback path only)
// ---------------------------------------------------------------------------
__global__ void bcast8(const float4* __restrict__ src, float4* __restrict__ dst)
{
    const long long slice4 = (long long)N_OBJ * HDIM / 4;
    long long i = (long long)blockIdx.x * blockDim.x + threadIdx.x;
    float4 v = src[i];
#pragma unroll
    for (int c = 1; c < BATCH; ++c)
        dst[c * slice4 + i] = v;
}

// ---------------------------------------------------------------------------
extern "C" void kernel_launch(void* const* d_in, const int* in_sizes, int n_in,
                              void* d_out, int out_size, void* d_ws, size_t ws_size,
                              hipStream_t stream)
{
    const float* feat_object = (const float*)d_in[1];
    const float* feat_room   = (const float*)d_in[2];
    const float* feat_attr   = (const float*)d_in[3];
    const float* W1i = (const float*)d_in[4];
    const float* b1i = (const float*)d_in[5];
    const float* W1b = (const float*)d_in[6];
    const float* b1b = (const float*)d_in[7];
    const float* W2  = (const float*)d_in[8];
    const float* b2  = (const float*)d_in[9];
    const int* src_oo = (const int*)d_in[10];
    const int* dst_oo = (const int*)d_in[11];
    const int* src_ro = (const int*)d_in[12];
    const int* dst_ro = (const int*)d_in[13];
    const int* src_ao = (const int*)d_in[14];
    const int* dst_ao = (const int*)d_in[15];
    float* out = (float*)d_out;

    const size_t slice = (size_t)N_OBJ * HDIM;
    const int KP1 = 320;
    const int KP2 = 512;

    // ~170 MB scratch. Prefer d_ws (measured ~1.31 GB); else d_out slices 1..7.
    const size_t NEED = 200u * 1024u * 1024u;
    bool use_ws = (ws_size >= NEED);
    char* base = use_ws ? (char*)d_ws : (char*)(out + slice);
    size_t off = 0;
    auto alloc = [&](size_t bytes) -> void* {
        void* p = base + off;
        off += (bytes + 255) & ~(size_t)255;
        return p;
    };

    float* n_src_oo = (float*)alloc(N_OBJ  * 4);
    float* n_src_ro = (float*)alloc(N_ROOM * 4);
    float* n_src_ao = (float*)alloc(N_ATTR * 4);
    float* n_dst_oo = (float*)alloc(N_OBJ * 4);
    float* n_dst_ro = (float*)alloc(N_OBJ * 4);
    float* n_dst_ao = (float*)alloc(N_OBJ * 4);

    const int CNT_TOTAL = N_OBJ + 512 + 2048 + 3 * N_OBJ;
    int* cnt_blk    = (int*)alloc((size_t)CNT_TOTAL * 4);
    int* cnt_src_oo = cnt_blk;
    int* cnt_src_ro = cnt_src_oo + N_OBJ;
    int* cnt_src_ao = cnt_src_ro + 512;
    int* cnt_dst_oo = cnt_src_ao + 2048;
    int* cnt_dst_ro = cnt_dst_oo + N_OBJ;
    int* cnt_dst_ao = cnt_dst_ro + N_OBJ;

    int* rp_oo  = (int*)alloc((N_OBJ + 1) * 4);
    int* rp_ro  = (int*)alloc((N_OBJ + 1) * 4);
    int* rp_ao  = (int*)alloc((N_OBJ + 1) * 4);
    int* cur_oo = (int*)alloc(N_OBJ * 4);
    int* cur_ro = (int*)alloc(N_OBJ * 4);
    int* cur_ao = (int*)alloc(N_OBJ * 4);
    int* col_oo = (int*)alloc((size_t)E_OO * 4);
    int* col_ro = (int*)alloc((size_t)E_RO * 4);
    int* col_ao = (int*)alloc((size_t)E_AO * 4);

    unsigned short* AhO = (unsigned short*)alloc((size_t)N_OBJ * KP1 * 2);
    unsigned short* AlO = (unsigned short*)alloc((size_t)N_OBJ * KP1 * 2);
    unsigned short* AhR = (unsigned short*)alloc((size_t)N_OBJ * KP1 * 2);
    unsigned short* AlR = (unsigned short*)alloc((size_t)N_OBJ * KP1 * 2);
    unsigned short* AhAt = (unsigned short*)alloc((size_t)N_OBJ * KP1 * 2);
    unsigned short* AlAt = (unsigned short*)alloc((size_t)N_OBJ * KP1 * 2);
    unsigned short* Ah2 = (unsigned short*)alloc((size_t)N_OBJ * KP2 * 2);
    unsigned short* Al2 = (unsigned short*)alloc((size_t)N_OBJ * KP2 * 2);
    unsigned short* Wp1i = (unsigned short*)alloc((size_t)HDIM * 3 * KP1 * 2);
    unsigned short* Wp1b = (unsigned short*)alloc((size_t)HDIM * 3 * KP1 * 2);
    unsigned short* Wp2  = (unsigned short*)alloc((size_t)HDIM * 3 * KP2 * 2);
    float* h_sum = (float*)alloc(slice * 4);

    // ---- CSR build ----
    hipMemsetAsync(cnt_blk, 0, (size_t)CNT_TOTAL * 4, stream);
    const int TOTAL_E = E_OO + E_RO + E_AO;
    int egrid = (TOTAL_E + 255) / 256;
    count_edges<<<egrid, 256, 0, stream>>>(src_oo, dst_oo, src_ro, dst_ro, src_ao, dst_ao,
                                           cnt_src_oo, cnt_src_ro, cnt_src_ao,
                                           cnt_dst_oo, cnt_dst_ro, cnt_dst_ao);
    scan3<<<3, 1024, 0, stream>>>(cnt_dst_oo, cnt_dst_ro, cnt_dst_ao,
                                  rp_oo, rp_ro, rp_ao, cur_oo, cur_ro, cur_ao);
    norms6<<<dim3((N_OBJ + 255) / 256, 6), 256, 0, stream>>>(
        cnt_src_oo, cnt_src_ro, cnt_src_ao, cnt_dst_oo, cnt_dst_ro, cnt_dst_ao,
        n_src_oo, n_src_ro, n_src_ao, n_dst_oo, n_dst_ro, n_dst_ao,
        N_OBJ, N_ROOM, N_ATTR, N_OBJ, N_OBJ, N_OBJ);
    fill_edges<<<egrid, 256, 0, stream>>>(src_oo, dst_oo, src_ro, dst_ro, src_ao, dst_ao,
                                          cur_oo, cur_ro, cur_ao, col_oo, col_ro, col_ao);

    // ---- weight packing ----
    {
        int e1 = HDIM * 3 * KP1, e2 = HDIM * 3 * KP2;
        pack_w<<<(e1 + 255) / 256, 256, 0, stream>>>(W1i, IN_F, KP1, Wp1i);
        pack_w<<<(e1 + 255) / 256, 256, 0, stream>>>(W1b, IN_F, KP1, Wp1b);
        pack_w<<<(e2 + 255) / 256, 256, 0, stream>>>(W2, HDIM, KP2, Wp2);
    }

    // ---- conv1 aggregations (independent) ----
    int agrid = (N_OBJ + 3) / 4;
    agg_split_v4<IN_F, 320><<<agrid, 256, 0, stream>>>(feat_object, rp_oo, col_oo,
                                                       n_src_oo, n_dst_oo, 1.0f, AhO, AlO);
    agg_split_v4<IN_F, 320><<<agrid, 256, 0, stream>>>(feat_room, rp_ro, col_ro,
                                                       n_src_ro, n_dst_ro, 1.0f, AhR, AlR);
    agg_split_v4<IN_F, 320><<<agrid, 256, 0, stream>>>(feat_attr, rp_ao, col_ao,
                                                       n_src_ao, n_dst_ao, 1.0f, AhAt, AlAt);

    // ---- conv1 fused GEMM: h_sum = sum_r relu(A_r @ W_r + b_r) ----
    dim3 ggrid((N_OBJ + 127) / 128, HDIM / 128);
    gemm_pipe<KP1, 3, 0><<<ggrid, 256, 0, stream>>>(
        AhO, AlO, AhR, AlR, AhAt, AlAt, Wp1i, Wp1b, b1i, b1b, h_sum, N_OBJ);

    // ---- conv2: oo graph on h_obj = h_sum/3 (scale folded into agg) ----
    agg_split_v4<HDIM, HDIM><<<agrid, 256, 0, stream>>>(h_sum, rp_oo, col_oo,
                                                        n_src_oo, n_dst_oo, 1.0f / 3.0f,
                                                        Ah2, Al2);
    if (use_ws) {
        gemm_pipe<KP2, 1, 2><<<ggrid, 256, 0, stream>>>(
            Ah2, Al2, Ah2, Al2, Ah2, Al2, Wp2, Wp2, b2, b2, out, N_OBJ);
    } else {
        gemm_pipe<KP2, 1, 3><<<ggrid, 256, 0, stream>>>(
            Ah2, Al2, Ah2, Al2, Ah2, Al2, Wp2, Wp2, b2, b2, out, N_OBJ);
        const long long slice4 = (long long)slice / 4;
        bcast8<<<(unsigned)(slice4 / 256), 256, 0, stream>>>((const float4*)out, (float4*)out);
    }
}